// Round 1
// baseline (3418.254 us; speedup 1.0000x reference)
//
#include <hip/hip_runtime.h>
#include <hip/hip_bf16.h>
#include <stdint.h>

#define NV 100000   // nodes
#define NT 8        // edge types
#define NE 400000   // edges per type
#define ND 128      // feature dim

// ---------------- ws layout (bytes) ----------------
// [0, NT*NV*4)                cnt_src  -> inv_ns (f32, in place)
// [NT*NV*4, 2*NT*NV*4)        cnt_dst  -> inv_nd (f32, in place)
// [2*NT*NV*4, +NT*NV*ND*2)    Y (bf16 as ushort): Y[t][v][d]
// total = 6.4MB + 204.8MB = 211.2MB

static __device__ __forceinline__ unsigned short f2bf(float f) {
    unsigned u = __float_as_uint(f);
    u += 0x7fffu + ((u >> 16) & 1u);   // RNE
    return (unsigned short)(u >> 16);
}

__global__ __launch_bounds__(256) void k_count(const int* __restrict__ edges,
                                               unsigned* __restrict__ cs,
                                               unsigned* __restrict__ cd) {
    int i = blockIdx.x * 256 + threadIdx.x;
    if (i >= NT * NE) return;
    int t = i / NE;
    int e = i - t * NE;
    const int* base = edges + (size_t)t * 2 * NE;
    int s = base[e];
    int d = base[NE + e];
    atomicAdd(&cs[t * NV + s], 1u);
    atomicAdd(&cd[t * NV + d], 1u);
}

__global__ __launch_bounds__(256) void k_inv(unsigned* __restrict__ cs,
                                             unsigned* __restrict__ cd) {
    int i = blockIdx.x * 256 + threadIdx.x;
    if (i >= NT * NV) return;
    unsigned a = cs[i];
    unsigned b = cd[i];
    ((float*)cs)[i] = rsqrtf((float)(a > 1u ? a : 1u));
    ((float*)cd)[i] = rsqrtf((float)(b > 1u ? b : 1u));
}

// Y[t][v][:] = (x[v] @ W_t) * inv_ns[t][v], stored bf16.
// grid = (ceil(NV/128), NT), block = 256. Tile: 128 rows x 128 cols, K=128.
__global__ __launch_bounds__(256) void k_ygemm(const float* __restrict__ x,
                                               const float* __restrict__ W,
                                               const float* __restrict__ inv_ns,
                                               unsigned short* __restrict__ Y) {
    __shared__ float xs[128][128];  // 64 KB
    __shared__ float ws[128][128];  // 64 KB
    const int t    = blockIdx.y;
    const int row0 = blockIdx.x * 128;
    const int tid  = threadIdx.x;

    // load W_t tile: ws[k][j] = W[(t*128+k)*128 + j]
#pragma unroll
    for (int it = 0; it < 16; ++it) {
        int idx = (it * 256 + tid) * 4;
        int k = idx >> 7, j = idx & 127;
        *(float4*)&ws[k][j] = *(const float4*)&W[(size_t)(t * 128 + k) * 128 + j];
    }
    // load x tile (row-guarded)
#pragma unroll
    for (int it = 0; it < 16; ++it) {
        int idx = (it * 256 + tid) * 4;
        int r = idx >> 7, c = idx & 127;
        int row = row0 + r;
        float4 v = make_float4(0.f, 0.f, 0.f, 0.f);
        if (row < NV) v = *(const float4*)&x[(size_t)row * 128 + c];
        *(float4*)&xs[r][c] = v;
    }
    __syncthreads();

    const int rr = (tid >> 4) * 8;   // 16 row groups of 8
    const int cc = (tid & 15) * 8;   // 16 col groups of 8
    float acc[8][8];
#pragma unroll
    for (int i = 0; i < 8; ++i)
#pragma unroll
        for (int j = 0; j < 8; ++j) acc[i][j] = 0.f;

    for (int k = 0; k < 128; ++k) {
        float a[8], bv[8];
#pragma unroll
        for (int i = 0; i < 8; ++i) a[i] = xs[rr + i][k];
        *(float4*)&bv[0] = *(const float4*)&ws[k][cc];
        *(float4*)&bv[4] = *(const float4*)&ws[k][cc + 4];
#pragma unroll
        for (int i = 0; i < 8; ++i)
#pragma unroll
            for (int j = 0; j < 8; ++j)
                acc[i][j] = fmaf(a[i], bv[j], acc[i][j]);
    }

#pragma unroll
    for (int i = 0; i < 8; ++i) {
        int row = row0 + rr + i;
        if (row < NV) {
            float s = inv_ns[t * NV + row];
            union { unsigned short us[8]; uint4 v4; } pk;
#pragma unroll
            for (int j = 0; j < 8; ++j) pk.us[j] = f2bf(acc[i][j] * s);
            *(uint4*)&Y[((size_t)t * NV + row) * ND + cc] = pk.v4;
        }
    }
}

__global__ __launch_bounds__(256) void k_init(const float* __restrict__ b,
                                              float* __restrict__ out) {
    int i = blockIdx.x * 256 + threadIdx.x;   // grid sized exactly NV*ND/256
    out[i] = b[i & (ND - 1)];
}

// one wave (64 lanes) per edge; lane handles 2 consecutive feature elems
__global__ __launch_bounds__(256) void k_scatter(const int* __restrict__ edges,
                                                 const unsigned* __restrict__ Yu,
                                                 const float* __restrict__ inv_nd,
                                                 float* __restrict__ out) {
    int gw   = (blockIdx.x * 256 + threadIdx.x) >> 6;  // global wave id = edge id
    int lane = threadIdx.x & 63;
    int t = gw / NE;
    int e = gw - t * NE;
    const int* base = edges + (size_t)t * 2 * NE;
    int s = base[e];
    int d = base[NE + e];
    float sc = inv_nd[t * NV + d];
    unsigned u = Yu[((size_t)t * NV + s) * (ND / 2) + lane];  // 2 bf16
    float f0 = __uint_as_float(u << 16) * sc;
    float f1 = __uint_as_float(u & 0xffff0000u) * sc;
    float* o = out + (size_t)d * ND + lane * 2;
    atomicAdd(o, f0);
    atomicAdd(o + 1, f1);
}

extern "C" void kernel_launch(void* const* d_in, const int* in_sizes, int n_in,
                              void* d_out, int out_size, void* d_ws, size_t ws_size,
                              hipStream_t stream) {
    const float* x     = (const float*)d_in[0];
    const int*   edges = (const int*)d_in[1];
    const float* W     = (const float*)d_in[2];
    const float* b     = (const float*)d_in[3];
    float*       out   = (float*)d_out;

    const size_t need = (size_t)2 * NT * NV * 4 + (size_t)NT * NV * ND * 2;
    if (ws_size < need) return;  // ws too small: leave output poisoned -> visible failure mode

    unsigned*       cs = (unsigned*)d_ws;
    unsigned*       cd = cs + (size_t)NT * NV;
    unsigned short* Y  = (unsigned short*)(cd + (size_t)NT * NV);

    hipMemsetAsync(d_ws, 0, (size_t)2 * NT * NV * sizeof(unsigned), stream);
    k_count<<<(NT * NE + 255) / 256, 256, 0, stream>>>(edges, cs, cd);
    k_inv<<<(NT * NV + 255) / 256, 256, 0, stream>>>(cs, cd);
    k_ygemm<<<dim3((NV + 127) / 128, NT), 256, 0, stream>>>(x, W, (const float*)cs, Y);
    k_init<<<(NV * ND) / 256, 256, 0, stream>>>(b, out);
    k_scatter<<<(NT * NE) / 4, 256, 0, stream>>>(edges, (const unsigned*)Y, (const float*)cd, out);
}

// Round 2
// 1301.913 us; speedup vs baseline: 2.6256x; 2.6256x over previous
//
#include <hip/hip_runtime.h>
#include <hip/hip_bf16.h>
#include <stdint.h>

#define NV 100000   // nodes
#define NT 8        // edge types
#define NE 400000   // edges per type
#define ND 128      // feature dim
#define NTV (NT * NV)                 // 800000 (t,v) pairs
#define SC1B ((NTV + 1023) / 1024)    // 782 scan blocks

typedef float  f32x4  __attribute__((ext_vector_type(4)));
typedef short  bf16x8 __attribute__((ext_vector_type(8)));

static __device__ __forceinline__ unsigned short f2bf(float f) {
    unsigned u = __float_as_uint(f);
    u += 0x7fffu + ((u >> 16) & 1u);   // RNE
    return (unsigned short)(u >> 16);
}

// degree counts for src (cs) and dest (cd)
__global__ __launch_bounds__(256) void k_count(const int* __restrict__ edges,
                                               unsigned* __restrict__ cs,
                                               unsigned* __restrict__ cd) {
    int i = blockIdx.x * 256 + threadIdx.x;
    if (i >= NT * NE) return;
    int t = i / NE;
    int e = i - t * NE;
    const int* base = edges + (size_t)t * 2 * NE;
    atomicAdd(&cs[t * NV + base[e]], 1u);
    atomicAdd(&cd[t * NV + base[NE + e]], 1u);
}

// cs counts -> inv_ns (f32, in place)
__global__ __launch_bounds__(256) void k_inv(unsigned* __restrict__ cs) {
    int i = blockIdx.x * 256 + threadIdx.x;
    if (i >= NTV) return;
    unsigned a = cs[i];
    ((float*)cs)[i] = rsqrtf((float)(a > 1u ? a : 1u));
}

// ---- exclusive scan of cd (800000 u32) -> off, 3 kernels ----
__global__ __launch_bounds__(256) void k_scan1(const unsigned* __restrict__ cnt,
                                               unsigned* __restrict__ off,
                                               unsigned* __restrict__ bsum) {
    __shared__ unsigned sm[256];
    int tid  = threadIdx.x;
    int base = blockIdx.x * 1024 + tid * 4;
    unsigned v0 = (base + 0 < NTV) ? cnt[base + 0] : 0u;
    unsigned v1 = (base + 1 < NTV) ? cnt[base + 1] : 0u;
    unsigned v2 = (base + 2 < NTV) ? cnt[base + 2] : 0u;
    unsigned v3 = (base + 3 < NTV) ? cnt[base + 3] : 0u;
    unsigned s4 = v0 + v1 + v2 + v3;
    sm[tid] = s4;
    __syncthreads();
    for (int d = 1; d < 256; d <<= 1) {
        unsigned tv = (tid >= d) ? sm[tid - d] : 0u;
        __syncthreads();
        sm[tid] += tv;
        __syncthreads();
    }
    unsigned excl = sm[tid] - s4;
    if (tid == 255) bsum[blockIdx.x] = sm[255];
    if (base + 0 < NTV) off[base + 0] = excl;
    if (base + 1 < NTV) off[base + 1] = excl + v0;
    if (base + 2 < NTV) off[base + 2] = excl + v0 + v1;
    if (base + 3 < NTV) off[base + 3] = excl + v0 + v1 + v2;
}

__global__ __launch_bounds__(1024) void k_scan2(unsigned* __restrict__ bsum) {
    __shared__ unsigned sm[1024];
    int tid = threadIdx.x;
    unsigned v = (tid < SC1B) ? bsum[tid] : 0u;
    sm[tid] = v;
    __syncthreads();
    for (int d = 1; d < 1024; d <<= 1) {
        unsigned tv = (tid >= d) ? sm[tid - d] : 0u;
        __syncthreads();
        sm[tid] += tv;
        __syncthreads();
    }
    if (tid < SC1B) bsum[tid] = sm[tid] - v;   // exclusive
}

__global__ __launch_bounds__(256) void k_scan3(unsigned* __restrict__ off,
                                               const unsigned* __restrict__ bsum,
                                               unsigned* __restrict__ cursor) {
    int i = blockIdx.x * 256 + threadIdx.x;
    if (i < NTV) {
        unsigned v = off[i] + bsum[i >> 10];
        off[i]    = v;
        cursor[i] = v;
    }
    if (i == 0) off[NTV] = (unsigned)(NT * NE);
}

// W [T*D][D] f32 -> Wt [T][col][k] bf16 (transposed per type)
__global__ __launch_bounds__(256) void k_cvtw(const float* __restrict__ W,
                                              unsigned short* __restrict__ Wt) {
    int i = blockIdx.x * 256 + threadIdx.x;     // NT*ND*ND = 131072
    int t = i >> 14;
    int r = i & 16383;
    int col = r >> 7;
    int k   = r & 127;
    Wt[i] = f2bf(W[((size_t)t * 128 + k) * 128 + col]);
}

// CSR fill: bucket src by (t, dest)
__global__ __launch_bounds__(256) void k_fill(const int* __restrict__ edges,
                                              unsigned* __restrict__ cursor,
                                              int* __restrict__ elist) {
    int i = blockIdx.x * 256 + threadIdx.x;
    if (i >= NT * NE) return;
    int t = i / NE;
    int e = i - t * NE;
    const int* base = edges + (size_t)t * 2 * NE;
    int s = base[e];
    int d = base[NE + e];
    unsigned pos = atomicAdd(&cursor[t * NV + d], 1u);
    elist[pos] = s;
}

// fused gather + (agg * inv_nd) @ W_t, accumulated over t in MFMA regs.
// block = 256 (4 waves); wave owns 16 dest rows; grid.x = ceil(NV/64).
__global__ __launch_bounds__(256) void k_fused(
    const float* __restrict__ x, const unsigned short* __restrict__ Wt,
    const float* __restrict__ inv_ns, const unsigned* __restrict__ off,
    const int* __restrict__ elist, const float* __restrict__ bias,
    float* __restrict__ out)
{
    __shared__ float agg[4][16][128];          // 32 KB, per-wave 8KB region
    const int wid  = threadIdx.x >> 6;
    const int lane = threadIdx.x & 63;
    const int row0 = blockIdx.x * 64 + wid * 16;
    char* aggb = (char*)&agg[wid][0][0];

    const int arow = lane & 15;   // A-frag row / C-D col
    const int g    = lane >> 4;

    f32x4 acc[8];
#pragma unroll
    for (int cf = 0; cf < 8; ++cf) acc[cf] = (f32x4){0.f, 0.f, 0.f, 0.f};

    for (int t = 0; t < NT; ++t) {
        // zero this wave's agg region (8 KB)
#pragma unroll
        for (int it = 0; it < 8; ++it)
            *(float4*)(aggb + it * 1024 + lane * 16) = make_float4(0.f, 0.f, 0.f, 0.f);

        // gather: for each of my 16 dest rows, sum x[src]*inv_ns over edges
        for (int r = 0; r < 16; ++r) {
            int row = row0 + r;
            if (row >= NV) break;             // tail rows stay zero
            int i = t * NV + row;
            unsigned e0 = off[i], e1 = off[i + 1];
            unsigned a = ((unsigned)(r * 512 + lane * 8)) ^ (((unsigned)(r & 7)) << 4);
            float2* slot = (float2*)(aggb + a);
            float2 cur = *slot;               // zeros
            for (unsigned e = e0; e < e1; ++e) {
                int   src = elist[e];
                float sns = inv_ns[t * NV + src];
                float2 xv = *(const float2*)&x[(size_t)src * ND + lane * 2];
                cur.x = fmaf(xv.x, sns, cur.x);
                cur.y = fmaf(xv.y, sns, cur.y);
            }
            *slot = cur;
        }

        // inv_nd for my A-row (dest-degree from off diff)
        int crow = row0 + arow;
        int ci   = t * NV + (crow < NV ? crow : NV - 1);
        unsigned dd = off[ci + 1] - off[ci];
        float snd = rsqrtf((float)(dd > 1u ? dd : 1u));

        // A-frag from LDS (bf16), B-frag from Wt, 32 MFMAs for this type
#pragma unroll
        for (int ks = 0; ks < 4; ++ks) {
            unsigned rb = (unsigned)(arow * 512 + ks * 128 + g * 32);
            unsigned sw = ((unsigned)(arow & 7)) << 4;
            float4 lo = *(float4*)(aggb + ((rb)      ^ sw));
            float4 hi = *(float4*)(aggb + ((rb + 16) ^ sw));
            union { unsigned short u[8]; bf16x8 v; } af;
            af.u[0] = f2bf(lo.x * snd); af.u[1] = f2bf(lo.y * snd);
            af.u[2] = f2bf(lo.z * snd); af.u[3] = f2bf(lo.w * snd);
            af.u[4] = f2bf(hi.x * snd); af.u[5] = f2bf(hi.y * snd);
            af.u[6] = f2bf(hi.z * snd); af.u[7] = f2bf(hi.w * snd);
#pragma unroll
            for (int cf = 0; cf < 8; ++cf) {
                const bf16x8 bf = *(const bf16x8*)&Wt[((size_t)(t * 128 + cf * 16 + arow)) * 128 + ks * 32 + g * 8];
                acc[cf] = __builtin_amdgcn_mfma_f32_16x16x32_bf16(af.v, bf, acc[cf], 0, 0, 0);
            }
        }
    }

    // epilogue: C/D layout col = lane&15, row = (lane>>4)*4 + i  [HW-verified]
#pragma unroll
    for (int i = 0; i < 4; ++i) {
        int row = row0 + g * 4 + i;
        if (row < NV) {
#pragma unroll
            for (int cf = 0; cf < 8; ++cf)
                out[(size_t)row * ND + cf * 16 + arow] = acc[cf][i] + bias[cf * 16 + arow];
        }
    }
}

extern "C" void kernel_launch(void* const* d_in, const int* in_sizes, int n_in,
                              void* d_out, int out_size, void* d_ws, size_t ws_size,
                              hipStream_t stream) {
    const float* x     = (const float*)d_in[0];
    const int*   edges = (const int*)d_in[1];
    const float* W     = (const float*)d_in[2];
    const float* b     = (const float*)d_in[3];
    float*       out   = (float*)d_out;

    // ws layout: Wt (16B-aligned, 256KB) | cs | cd | off | bsum | cursor | elist
    unsigned short* Wt     = (unsigned short*)d_ws;
    unsigned*       cs     = (unsigned*)((char*)d_ws + (size_t)NT * ND * ND * 2);
    unsigned*       cd     = cs + NTV;
    unsigned*       off    = cd + NTV;          // NTV+1
    unsigned*       bsum   = off + NTV + 1;     // 1024
    unsigned*       cursor = bsum + 1024;
    int*            elist  = (int*)(cursor + NTV);

    const size_t need = (size_t)NT * ND * ND * 2 +
                        ((size_t)3 * NTV + (NTV + 1) + 1024 + (size_t)NT * NE) * 4;
    if (ws_size < need) return;

    hipMemsetAsync(cs, 0, (size_t)2 * NTV * sizeof(unsigned), stream);
    k_count<<<(NT * NE) / 256, 256, 0, stream>>>(edges, cs, cd);
    k_scan1<<<SC1B, 256, 0, stream>>>(cd, off, bsum);
    k_scan2<<<1, 1024, 0, stream>>>(bsum);
    k_scan3<<<(NTV + 255) / 256, 256, 0, stream>>>(off, bsum, cursor);
    k_inv<<<(NTV + 255) / 256, 256, 0, stream>>>(cs);
    k_cvtw<<<(NT * ND * ND) / 256, 256, 0, stream>>>(W, Wt);
    k_fill<<<(NT * NE) / 256, 256, 0, stream>>>(edges, cursor, elist);
    k_fused<<<(NV + 63) / 64, 256, 0, stream>>>(x, Wt, (const float*)cs, off, elist, b, out);
}

// Round 3
// 833.838 us; speedup vs baseline: 4.0994x; 1.5613x over previous
//
#include <hip/hip_runtime.h>
#include <hip/hip_bf16.h>
#include <stdint.h>

#define NV 100000   // nodes
#define NT 8        // edge types
#define NE 400000   // edges per type
#define ND 128      // feature dim
#define NTV (NT * NV)                 // 800000 (t,v) pairs
#define SC1B ((NTV + 1023) / 1024)    // 782 scan blocks

typedef float  f32x4  __attribute__((ext_vector_type(4)));
typedef short  bf16x8 __attribute__((ext_vector_type(8)));

static __device__ __forceinline__ unsigned short f2bf(float f) {
    unsigned u = __float_as_uint(f);
    u += 0x7fffu + ((u >> 16) & 1u);   // RNE
    return (unsigned short)(u >> 16);
}

// degree counts for src (cs) and dest (cd)
__global__ __launch_bounds__(256) void k_count(const int* __restrict__ edges,
                                               unsigned* __restrict__ cs,
                                               unsigned* __restrict__ cd) {
    int i = blockIdx.x * 256 + threadIdx.x;
    if (i >= NT * NE) return;
    int t = i / NE;
    int e = i - t * NE;
    const int* base = edges + (size_t)t * 2 * NE;
    atomicAdd(&cs[t * NV + base[e]], 1u);
    atomicAdd(&cd[t * NV + base[NE + e]], 1u);
}

// ---- exclusive scan of cd (800000 u32) -> off, 3 kernels ----
__global__ __launch_bounds__(256) void k_scan1(const unsigned* __restrict__ cnt,
                                               unsigned* __restrict__ off,
                                               unsigned* __restrict__ bsum) {
    __shared__ unsigned sm[256];
    int tid  = threadIdx.x;
    int base = blockIdx.x * 1024 + tid * 4;
    unsigned v0 = (base + 0 < NTV) ? cnt[base + 0] : 0u;
    unsigned v1 = (base + 1 < NTV) ? cnt[base + 1] : 0u;
    unsigned v2 = (base + 2 < NTV) ? cnt[base + 2] : 0u;
    unsigned v3 = (base + 3 < NTV) ? cnt[base + 3] : 0u;
    unsigned s4 = v0 + v1 + v2 + v3;
    sm[tid] = s4;
    __syncthreads();
    for (int d = 1; d < 256; d <<= 1) {
        unsigned tv = (tid >= d) ? sm[tid - d] : 0u;
        __syncthreads();
        sm[tid] += tv;
        __syncthreads();
    }
    unsigned excl = sm[tid] - s4;
    if (tid == 255) bsum[blockIdx.x] = sm[255];
    if (base + 0 < NTV) off[base + 0] = excl;
    if (base + 1 < NTV) off[base + 1] = excl + v0;
    if (base + 2 < NTV) off[base + 2] = excl + v0 + v1;
    if (base + 3 < NTV) off[base + 3] = excl + v0 + v1 + v2;
}

__global__ __launch_bounds__(1024) void k_scan2(unsigned* __restrict__ bsum) {
    __shared__ unsigned sm[1024];
    int tid = threadIdx.x;
    unsigned v = (tid < SC1B) ? bsum[tid] : 0u;
    sm[tid] = v;
    __syncthreads();
    for (int d = 1; d < 1024; d <<= 1) {
        unsigned tv = (tid >= d) ? sm[tid - d] : 0u;
        __syncthreads();
        sm[tid] += tv;
        __syncthreads();
    }
    if (tid < SC1B) bsum[tid] = sm[tid] - v;   // exclusive
}

// scan finalize + cursor copy + inv_ns (fused)
__global__ __launch_bounds__(256) void k_scan3(unsigned* __restrict__ off,
                                               const unsigned* __restrict__ bsum,
                                               unsigned* __restrict__ cursor,
                                               unsigned* __restrict__ cs) {
    int i = blockIdx.x * 256 + threadIdx.x;
    if (i < NTV) {
        unsigned v = off[i] + bsum[i >> 10];
        off[i]    = v;
        cursor[i] = v;
        unsigned a = cs[i];
        ((float*)cs)[i] = rsqrtf((float)(a > 1u ? a : 1u));
    }
    if (i == 0) off[NTV] = (unsigned)(NT * NE);
}

// W [T*D][D] f32 -> Wt [T][col][k] bf16 (transposed per type)
__global__ __launch_bounds__(256) void k_cvtw(const float* __restrict__ W,
                                              unsigned short* __restrict__ Wt) {
    int i = blockIdx.x * 256 + threadIdx.x;     // NT*ND*ND = 131072
    int t = i >> 14;
    int r = i & 16383;
    int col = r >> 7;
    int k   = r & 127;
    Wt[i] = f2bf(W[((size_t)t * 128 + k) * 128 + col]);
}

// x f32 -> bf16 (8 elems/thread)
__global__ __launch_bounds__(256) void k_cvtx(const float* __restrict__ x,
                                              unsigned short* __restrict__ xb) {
    int i = blockIdx.x * 256 + threadIdx.x;     // NV*ND/8 = 1.6M threads
    const float4 a = *(const float4*)&x[(size_t)i * 8];
    const float4 b = *(const float4*)&x[(size_t)i * 8 + 4];
    union { unsigned short us[8]; uint4 v; } pk;
    pk.us[0] = f2bf(a.x); pk.us[1] = f2bf(a.y);
    pk.us[2] = f2bf(a.z); pk.us[3] = f2bf(a.w);
    pk.us[4] = f2bf(b.x); pk.us[5] = f2bf(b.y);
    pk.us[6] = f2bf(b.z); pk.us[7] = f2bf(b.w);
    *(uint4*)&xb[(size_t)i * 8] = pk.v;
}

// CSR fill: bucket src by (t, dest)
__global__ __launch_bounds__(256) void k_fill(const int* __restrict__ edges,
                                              unsigned* __restrict__ cursor,
                                              int* __restrict__ elist) {
    int i = blockIdx.x * 256 + threadIdx.x;
    if (i >= NT * NE) return;
    int t = i / NE;
    int e = i - t * NE;
    const int* base = edges + (size_t)t * 2 * NE;
    int s = base[e];
    int d = base[NE + e];
    unsigned pos = atomicAdd(&cursor[t * NV + d], 1u);
    elist[pos] = s;
}

#define ACC8(dst, c, s)                                                      \
    do {                                                                     \
        (dst)[0] = fmaf(__uint_as_float((c).x << 16), (s), (dst)[0]);        \
        (dst)[1] = fmaf(__uint_as_float((c).x & 0xffff0000u), (s), (dst)[1]);\
        (dst)[2] = fmaf(__uint_as_float((c).y << 16), (s), (dst)[2]);        \
        (dst)[3] = fmaf(__uint_as_float((c).y & 0xffff0000u), (s), (dst)[3]);\
        (dst)[4] = fmaf(__uint_as_float((c).z << 16), (s), (dst)[4]);        \
        (dst)[5] = fmaf(__uint_as_float((c).z & 0xffff0000u), (s), (dst)[5]);\
        (dst)[6] = fmaf(__uint_as_float((c).w << 16), (s), (dst)[6]);        \
        (dst)[7] = fmaf(__uint_as_float((c).w & 0xffff0000u), (s), (dst)[7]);\
    } while (0)

// fused gather + (agg * inv_nd) @ W_t, accumulated over t in MFMA regs.
// NO LDS: each lane register-accumulates its A-fragment slice
// (row = lane&15 of the wave's 16 dest rows, k-chunks g*8 within each 32).
// All 16 rows' edge loops run concurrently (exec-masked).
__global__ __launch_bounds__(256, 4) void k_fused(
    const unsigned short* __restrict__ xb, const unsigned short* __restrict__ Wt,
    const float* __restrict__ inv_ns, const unsigned* __restrict__ off,
    const int* __restrict__ elist, const float* __restrict__ bias,
    float* __restrict__ out)
{
    const int lane  = threadIdx.x & 63;
    const int wid   = threadIdx.x >> 6;
    const int row0  = blockIdx.x * 64 + wid * 16;
    const int arow  = lane & 15;
    const int g     = lane >> 4;
    const int myrow = row0 + arow;
    const bool rowok = (myrow < NV);
    const int rowi  = rowok ? myrow : 0;

    f32x4 acc[8];
#pragma unroll
    for (int cf = 0; cf < 8; ++cf) acc[cf] = (f32x4){0.f, 0.f, 0.f, 0.f};

    for (int t = 0; t < NT; ++t) {
        float ga[32];
#pragma unroll
        for (int j = 0; j < 32; ++j) ga[j] = 0.f;

        const int ti = t * NV + rowi;
        unsigned e0 = off[ti];
        unsigned e1 = rowok ? off[ti + 1] : e0;
        unsigned dd = e1 - e0;
        float snd = rsqrtf((float)(dd > 1u ? dd : 1u));
        const float* insb = inv_ns + (size_t)t * NV;

        for (unsigned e = e0; e < e1; ++e) {
            int   src = elist[e];
            float sns = insb[src];
            const uint4* xp = (const uint4*)(xb + (size_t)src * ND) + g;
            uint4 c0 = xp[0];
            uint4 c1 = xp[4];
            uint4 c2 = xp[8];
            uint4 c3 = xp[12];
            ACC8(ga + 0,  c0, sns);
            ACC8(ga + 8,  c1, sns);
            ACC8(ga + 16, c2, sns);
            ACC8(ga + 24, c3, sns);
        }

#pragma unroll
        for (int ks = 0; ks < 4; ++ks) {
            union { unsigned short u[8]; bf16x8 v; } af;
#pragma unroll
            for (int j = 0; j < 8; ++j) af.u[j] = f2bf(ga[ks * 8 + j] * snd);
#pragma unroll
            for (int cf = 0; cf < 8; ++cf) {
                const bf16x8 bf = *(const bf16x8*)&Wt[((size_t)(t * 128 + cf * 16 + arow)) * 128 + ks * 32 + g * 8];
                acc[cf] = __builtin_amdgcn_mfma_f32_16x16x32_bf16(af.v, bf, acc[cf], 0, 0, 0);
            }
        }
    }

    // C/D layout: col = lane&15, row = (lane>>4)*4 + i  [HW-verified]
#pragma unroll
    for (int i2 = 0; i2 < 4; ++i2) {
        int row = row0 + g * 4 + i2;
        if (row < NV) {
#pragma unroll
            for (int cf = 0; cf < 8; ++cf)
                out[(size_t)row * ND + cf * 16 + arow] = acc[cf][i2] + bias[cf * 16 + arow];
        }
    }
}

extern "C" void kernel_launch(void* const* d_in, const int* in_sizes, int n_in,
                              void* d_out, int out_size, void* d_ws, size_t ws_size,
                              hipStream_t stream) {
    const float* x     = (const float*)d_in[0];
    const int*   edges = (const int*)d_in[1];
    const float* W     = (const float*)d_in[2];
    const float* b     = (const float*)d_in[3];
    float*       out   = (float*)d_out;

    // ws layout: xb (25.6MB) | Wt (256KB) | cs | cd | off(+1) | bsum | cursor | elist
    unsigned short* xb     = (unsigned short*)d_ws;
    unsigned short* Wt     = xb + (size_t)NV * ND;
    unsigned*       cs     = (unsigned*)(Wt + (size_t)NT * ND * ND);
    unsigned*       cd     = cs + NTV;
    unsigned*       off    = cd + NTV;          // NTV+1
    unsigned*       bsum   = off + NTV + 1;     // 1024
    unsigned*       cursor = bsum + 1024;
    int*            elist  = (int*)(cursor + NTV);

    const size_t need = (size_t)NV * ND * 2 + (size_t)NT * ND * ND * 2 +
                        ((size_t)3 * NTV + (NTV + 1) + 1024 + (size_t)NT * NE) * 4;
    if (ws_size < need) return;

    hipMemsetAsync(cs, 0, (size_t)2 * NTV * sizeof(unsigned), stream);
    k_count<<<(NT * NE) / 256, 256, 0, stream>>>(edges, cs, cd);
    k_scan1<<<SC1B, 256, 0, stream>>>(cd, off, bsum);
    k_scan2<<<1, 1024, 0, stream>>>(bsum);
    k_scan3<<<(NTV + 255) / 256, 256, 0, stream>>>(off, bsum, cursor, cs);
    k_cvtw<<<(NT * ND * ND) / 256, 256, 0, stream>>>(W, Wt);
    k_cvtx<<<(NV * ND / 8) / 256, 256, 0, stream>>>(x, xb);
    k_fill<<<(NT * NE) / 256, 256, 0, stream>>>(edges, cursor, elist);
    k_fused<<<(NV + 63) / 64, 256, 0, stream>>>(xb, Wt, (const float*)cs, off, elist, b, out);
}